// Round 8
// baseline (53.375 us; speedup 1.0000x reference)
//
#include <hip/hip_runtime.h>
#include <math.h>

#define Bn 64
#define Ln 350
#define Kn 8
#define Dn 300
#define Cn 20
#define SPLIT 16
#define PAD_IDX 1
#define NEG_BIG (-1e18f)

typedef float v4f __attribute__((ext_vector_type(4)));

__device__ __forceinline__ void mask_max(v4f& m, const v4f v, const float w) {
    float x0 = w * v.x, x1 = w * v.y, x2 = w * v.z, x3 = w * v.w;
    x0 = (x0 == 0.f) ? NEG_BIG : x0;
    x1 = (x1 == 0.f) ? NEG_BIG : x1;
    x2 = (x2 == 0.f) ? NEG_BIG : x2;
    x3 = (x3 == 0.f) ? NEG_BIG : x3;
    m.x = fmaxf(m.x, x0);
    m.y = fmaxf(m.y, x1);
    m.z = fmaxf(m.z, x2);
    m.w = fmaxf(m.w, x3);
}

// ---------------------------------------------------------------------------
// Kernel A: per (b,l): M[d] = max_k( mask(ew[k]*nbr[k,d]) ), combined =
// (1-ir)*M + ir*node_emb, accumulate sum over this block's l-slice.
// Block = 256 threads = 4 waves (wave = 64 lanes). SPLIT=16 -> 1024 blocks.
// TWO-ROW ILP: each wave processes rows in pairs (j = w+8t, j = w+4+8t) and
// issues both rows' 8 quad0 loads together (16 outstanding dwordx4/lane).
// NO min-waves launch bound: r4 showed capping VGPR serializes the loads
// (+20 us); r6 showed fused-epilogue codegen picking VGPR=56 runs 6x slower.
// ---------------------------------------------------------------------------
template <bool PARTIAL>
__global__ __launch_bounds__(256) void mp_reduce(
    const int* __restrict__ node_sets,
    const float* __restrict__ emb_node,
    const float* __restrict__ edge_w,
    const float* __restrict__ emb_nbr,
    const float* __restrict__ info_rate,
    float* __restrict__ ws)
{
    __shared__ __align__(16) float sAcc[4][Dn + 4];

    const int bid  = blockIdx.x;
    const int b    = bid / SPLIT;
    const int sidx = bid % SPLIT;
    const int tid  = threadIdx.x;
    const int wave = tid >> 6;   // 0..3
    const int lane = tid & 63;
    const bool has1 = (lane < (Dn / 4 - 64));   // 75 quads; 11 in tail
    const int q0 = 4 * lane;
    const int q1 = 256 + 4 * lane;

    v4f acc0 = (v4f)(0.f);
    v4f acc1 = (v4f)(0.f);

    for (int t = 0;; ++t) {
        const int j0 = wave + 8 * t;          // first row of the pair
        const int l0 = sidx + j0 * SPLIT;
        if (l0 >= Ln) break;
        const int l1 = l0 + 4 * SPLIT;        // second row (j0 + 4)
        const bool p1 = (l1 < Ln);            // wave-uniform

        const size_t r0 = (size_t)b * Ln + l0;
        const size_t r1 = r0 + 4 * SPLIT;

        // ---- scalars for both rows
        const v4f ea0 = *reinterpret_cast<const v4f*>(edge_w + r0 * Kn);
        const v4f ea1 = *reinterpret_cast<const v4f*>(edge_w + r0 * Kn + 4);
        const float ewA[Kn] = {ea0.x, ea0.y, ea0.z, ea0.w, ea1.x, ea1.y, ea1.z, ea1.w};
        const int nA = node_sets[r0];
        const float irA = (nA == PAD_IDX) ? 1.0f : info_rate[nA];
        const float omA = 1.0f - irA;
        const float* nbA = emb_nbr + r0 * (size_t)(Kn * Dn);
        const float* enA = emb_node + r0 * (size_t)Dn;

        float ewB[Kn];
        float irB = 1.0f, omB = 0.0f;
        const float* nbB = emb_nbr + r1 * (size_t)(Kn * Dn);
        const float* enB = emb_node + r1 * (size_t)Dn;
        if (p1) {
            const v4f eb0 = *reinterpret_cast<const v4f*>(edge_w + r1 * Kn);
            const v4f eb1 = *reinterpret_cast<const v4f*>(edge_w + r1 * Kn + 4);
            ewB[0]=eb0.x; ewB[1]=eb0.y; ewB[2]=eb0.z; ewB[3]=eb0.w;
            ewB[4]=eb1.x; ewB[5]=eb1.y; ewB[6]=eb1.z; ewB[7]=eb1.w;
            const int nB = node_sets[r1];
            irB = (nB == PAD_IDX) ? 1.0f : info_rate[nB];
            omB = 1.0f - irB;
        }

        // ---- issue ALL quad0 loads for both rows (16 independent dwordx4)
        v4f va[Kn];
        #pragma unroll
        for (int k = 0; k < Kn; ++k)
            va[k] = *reinterpret_cast<const v4f*>(nbA + k * Dn + q0);
        v4f vb[Kn];
        if (p1) {
            #pragma unroll
            for (int k = 0; k < Kn; ++k)
                vb[k] = *reinterpret_cast<const v4f*>(nbB + k * Dn + q0);
        }
        const v4f eA0 = *reinterpret_cast<const v4f*>(enA + q0);
        v4f eB0 = (v4f)(0.f);
        if (p1) eB0 = *reinterpret_cast<const v4f*>(enB + q0);

        // ---- compute row A quad0
        {
            v4f m = (v4f)(NEG_BIG);
            #pragma unroll
            for (int k = 0; k < Kn; ++k) mask_max(m, va[k], ewA[k]);
            acc0.x += omA * m.x + irA * eA0.x;
            acc0.y += omA * m.y + irA * eA0.y;
            acc0.z += omA * m.z + irA * eA0.z;
            acc0.w += omA * m.w + irA * eA0.w;
        }
        // ---- compute row B quad0
        if (p1) {
            v4f m = (v4f)(NEG_BIG);
            #pragma unroll
            for (int k = 0; k < Kn; ++k) mask_max(m, vb[k], ewB[k]);
            acc0.x += omB * m.x + irB * eB0.x;
            acc0.y += omB * m.y + irB * eB0.y;
            acc0.z += omB * m.z + irB * eB0.z;
            acc0.w += omB * m.w + irB * eB0.w;
        }

        // ---- quad1: d = 256 + 4*lane (lanes 0..10), both rows
        if (has1) {
            v4f wa[Kn];
            #pragma unroll
            for (int k = 0; k < Kn; ++k)
                wa[k] = *reinterpret_cast<const v4f*>(nbA + k * Dn + q1);
            v4f wb[Kn];
            if (p1) {
                #pragma unroll
                for (int k = 0; k < Kn; ++k)
                    wb[k] = *reinterpret_cast<const v4f*>(nbB + k * Dn + q1);
            }
            const v4f eA1 = *reinterpret_cast<const v4f*>(enA + q1);
            {
                v4f m = (v4f)(NEG_BIG);
                #pragma unroll
                for (int k = 0; k < Kn; ++k) mask_max(m, wa[k], ewA[k]);
                acc1.x += omA * m.x + irA * eA1.x;
                acc1.y += omA * m.y + irA * eA1.y;
                acc1.z += omA * m.z + irA * eA1.z;
                acc1.w += omA * m.w + irA * eA1.w;
            }
            if (p1) {
                const v4f eB1 = *reinterpret_cast<const v4f*>(enB + q1);
                v4f m = (v4f)(NEG_BIG);
                #pragma unroll
                for (int k = 0; k < Kn; ++k) mask_max(m, wb[k], ewB[k]);
                acc1.x += omB * m.x + irB * eB1.x;
                acc1.y += omB * m.y + irB * eB1.y;
                acc1.z += omB * m.z + irB * eB1.z;
                acc1.w += omB * m.w + irB * eB1.w;
            }
        }
    }

    // per-wave partials -> LDS (disjoint rows)
    *reinterpret_cast<v4f*>(&sAcc[wave][q0]) = acc0;
    if (has1) *reinterpret_cast<v4f*>(&sAcc[wave][q1]) = acc1;
    __syncthreads();

    if (PARTIAL) {
        float* dst = ws + (size_t)bid * Dn;
        for (int d = tid; d < Dn; d += 256)
            dst[d] = sAcc[0][d] + sAcc[1][d] + sAcc[2][d] + sAcc[3][d];
    } else {
        for (int d = tid; d < Dn; d += 256) {
            const float sum = sAcc[0][d] + sAcc[1][d] + sAcc[2][d] + sAcc[3][d];
            atomicAdd(&ws[b * Dn + d], sum);
        }
    }
}

// ---------------------------------------------------------------------------
// Kernel B: reduce NPART partials -> s[b,:], then
// x[b,c] = relu(dot(s, W[c]) + bias[c]); softmax over C=20. One block per b.
// Block = 256 threads = 4 WAVES.
// ---------------------------------------------------------------------------
template <int NPART>
__global__ __launch_bounds__(256) void mp_head(
    const float* __restrict__ part,
    const float* __restrict__ Wm,
    const float* __restrict__ bias,
    float* __restrict__ out)
{
    __shared__ __align__(16) float wsum[4][Dn + 4];
    __shared__ __align__(16) float ssh[Dn + 4];
    __shared__ float xsh[Cn];

    const int b = blockIdx.x;
    const int t = threadIdx.x;
    const int wave = t >> 6;   // 0..3
    const int lane = t & 63;
    const bool has1 = (lane < (Dn / 4 - 64));
    const int q0 = 4 * lane;
    const int q1 = 256 + 4 * lane;

    if (NPART >= 4) {
        constexpr int PPW = (NPART >= 4) ? NPART / 4 : 1;
        v4f a0 = (v4f)(0.f), a1 = (v4f)(0.f);
        #pragma unroll
        for (int p = 0; p < PPW; ++p) {
            const float* src = part + ((size_t)b * NPART + wave * PPW + p) * Dn;
            a0 += *reinterpret_cast<const v4f*>(src + q0);
            if (has1) a1 += *reinterpret_cast<const v4f*>(src + q1);
        }
        *reinterpret_cast<v4f*>(&wsum[wave][q0]) = a0;
        if (has1) *reinterpret_cast<v4f*>(&wsum[wave][q1]) = a1;
        __syncthreads();

        for (int d = t; d < Dn; d += 256)
            ssh[d] = wsum[0][d] + wsum[1][d] + wsum[2][d] + wsum[3][d];
    } else {
        for (int d = t; d < Dn; d += 256) ssh[d] = part[(size_t)b * Dn + d];
    }
    __syncthreads();

    for (int c = wave; c < Cn; c += 4) {
        const float* wr = Wm + (size_t)c * Dn;
        float acc = 0.f;
        {
            const v4f wv = *reinterpret_cast<const v4f*>(wr + q0);
            const v4f sv = *reinterpret_cast<const v4f*>(&ssh[q0]);
            acc += wv.x * sv.x + wv.y * sv.y + wv.z * sv.z + wv.w * sv.w;
        }
        if (has1) {
            const v4f wv = *reinterpret_cast<const v4f*>(wr + q1);
            const v4f sv = *reinterpret_cast<const v4f*>(&ssh[q1]);
            acc += wv.x * sv.x + wv.y * sv.y + wv.z * sv.z + wv.w * sv.w;
        }
        #pragma unroll
        for (int off = 32; off >= 1; off >>= 1)
            acc += __shfl_xor(acc, off, 64);
        if (lane == 0) xsh[c] = fmaxf(acc + bias[c], 0.f);
    }
    __syncthreads();

    if (t < Cn) {
        float mx = xsh[0];
        #pragma unroll
        for (int i = 1; i < Cn; ++i) mx = fmaxf(mx, xsh[i]);
        float sum = 0.f;
        #pragma unroll
        for (int i = 0; i < Cn; ++i) sum += expf(xsh[i] - mx);
        out[b * Cn + t] = expf(xsh[t] - mx) / sum;
    }
}

extern "C" void kernel_launch(void* const* d_in, const int* in_sizes, int n_in,
                              void* d_out, int out_size, void* d_ws, size_t ws_size,
                              hipStream_t stream) {
    const int*   node_sets = (const int*)d_in[0];
    const float* emb_node  = (const float*)d_in[1];
    const float* edge_w    = (const float*)d_in[2];
    const float* emb_nbr   = (const float*)d_in[3];
    const float* info_rate = (const float*)d_in[4];
    const float* Wm        = (const float*)d_in[5];
    const float* bias      = (const float*)d_in[6];
    float* out  = (float*)d_out;
    float* ws   = (float*)d_ws;

    const size_t need = (size_t)Bn * SPLIT * Dn * sizeof(float);
    if (ws_size >= need) {
        mp_reduce<true><<<dim3(Bn * SPLIT), 256, 0, stream>>>(
            node_sets, emb_node, edge_w, emb_nbr, info_rate, ws);
        mp_head<SPLIT><<<dim3(Bn), 256, 0, stream>>>(ws, Wm, bias, out);
    } else {
        hipMemsetAsync(d_ws, 0, (size_t)Bn * Dn * sizeof(float), stream);
        mp_reduce<false><<<dim3(Bn * SPLIT), 256, 0, stream>>>(
            node_sets, emb_node, edge_w, emb_nbr, info_rate, ws);
        mp_head<1><<<dim3(Bn), 256, 0, stream>>>(ws, Wm, bias, out);
    }
}